// Round 8
// baseline (518.704 us; speedup 1.0000x reference)
//
#include <hip/hip_runtime.h>

// ---------------------------------------------------------------------------
// ResNet sparse-conv block, round 11b (resubmit): proven R6 spconv schedule +
// float4 prep2 (no non-temporal ops anywhere). bn_relu_b16 deleted: BN2+ReLU
// fused into a SEPARATE conv2 kernel (spconv2bn) at A-consume time. Spill fix
// vs R8: __launch_bounds__(256,3) -> 170-reg cap (achieved occupancy ~10.4
// waves/CU < 12-wave cap, so free); non-template functions.
// ---------------------------------------------------------------------------

#define KOFF 27

typedef __bf16 bf16x8 __attribute__((ext_vector_type(8)));
typedef float floatx4 __attribute__((ext_vector_type(4)));

__device__ __forceinline__ unsigned short f2bf(float x) {
    union { float f; unsigned int u; } v; v.f = x;
    unsigned int u = v.u;
    unsigned int r = u + 0x7FFFu + ((u >> 16) & 1u);
    return (unsigned short)(r >> 16);
}
__device__ __forceinline__ float bf2f(unsigned short s) {
    union { float f; unsigned int u; } v; v.u = ((unsigned int)s) << 16; return v.f;
}

// --- prep: blocks 0..53 pack W (coalesced, LDS transpose); rest: x stats ----
// frag element j of (ct,ks) for lane (q,l15) = W[k][cin=ks*32+q*8+j][cout=ct*16+l15]
__global__ void prep2(const float* __restrict__ W1, const float* __restrict__ W2,
                      unsigned short* __restrict__ W1f, unsigned short* __restrict__ W2f,
                      const float* __restrict__ x, float* __restrict__ stats,
                      int total4) {
    int b = blockIdx.x, t = threadIdx.x;
    if (b < 54) {
        __shared__ float sW[64 * 68];
        int k = b % 27;
        const float* src = (b < 27 ? W1 : W2) + k * 4096;
        unsigned short* dst = (b < 27 ? W1f : W2f) + (size_t)k * 4096;
        #pragma unroll
        for (int i = 0; i < 4; ++i) {
            int i4 = t + i * 256;
            float4 v = ((const float4*)src)[i4];
            int f = i4 * 4, r = f >> 6, c = f & 63;
            sW[r * 68 + c]     = v.x;
            sW[r * 68 + c + 1] = v.y;
            sW[r * 68 + c + 2] = v.z;
            sW[r * 68 + c + 3] = v.w;
        }
        __syncthreads();
        int fi = (t >> 5) & 7, ct = fi >> 1, ks = fi & 1;
        unsigned short o[16];
        #pragma unroll
        for (int d = 0; d < 2; ++d) {
            int lane2 = (t * 2 + d) & 63, q = lane2 >> 4, l15 = lane2 & 15;
            #pragma unroll
            for (int j = 0; j < 8; ++j) {
                int cin = ks * 32 + q * 8 + j, cout = ct * 16 + l15;
                o[d * 8 + j] = f2bf(sW[cin * 68 + cout]);
            }
        }
        ((uint4*)(dst + t * 16))[0] = *(const uint4*)(o);
        ((uint4*)(dst + t * 16))[1] = *(const uint4*)(o + 8);
        return;
    }
    __shared__ float s[128];
    if (t < 128) s[t] = 0.f;
    __syncthreads();
    int i = (b - 54) * 256 + t;
    int stride = (gridDim.x - 54) * 256;
    // float4 loads; channel of component 0 is (4t)&63 (block/grid strides are
    // multiples of 64 channels).
    float a0 = 0.f, a1 = 0.f, a2 = 0.f, a3 = 0.f;
    float b0 = 0.f, b1 = 0.f, b2 = 0.f, b3 = 0.f;
    for (; i < total4; i += stride) {
        float4 v = ((const float4*)x)[i];
        a0 += v.x; b0 += v.x * v.x;
        a1 += v.y; b1 += v.y * v.y;
        a2 += v.z; b2 += v.z * v.z;
        a3 += v.w; b3 += v.w * v.w;
    }
    int c0 = (t << 2) & 63;
    atomicAdd(&s[c0],     a0); atomicAdd(&s[c0 + 1],     a1);
    atomicAdd(&s[c0 + 2], a2); atomicAdd(&s[c0 + 3],     a3);
    atomicAdd(&s[64 + c0],     b0); atomicAdd(&s[64 + c0 + 1], b1);
    atomicAdd(&s[64 + c0 + 2], b2); atomicAdd(&s[64 + c0 + 3], b3);
    __syncthreads();
    if (t < 64) { atomicAdd(&stats[t], s[t]); atomicAdd(&stats[64 + t], s[64 + t]); }
}

// --- BN + ReLU + bf16 cast, fp32 input --------------------------------------
__global__ void bn_relu_f32(const float* __restrict__ in, const float* __restrict__ sums,
                            const float* __restrict__ gamma, const float* __restrict__ beta,
                            unsigned short* __restrict__ out, int total4, float invN) {
    __shared__ float sab[128];
    int t = threadIdx.x;
    if (t < 64) {
        float mu  = sums[t] * invN;
        float var = fmaxf(sums[64 + t] * invN - mu * mu, 0.f);
        float a   = gamma[t] * rsqrtf(var + 1e-5f);
        sab[t] = a; sab[64 + t] = beta[t] - mu * a;
    }
    __syncthreads();
    int i = blockIdx.x * blockDim.x + t;
    int stride = gridDim.x * blockDim.x;
    for (; i < total4; i += stride) {
        float4 v = ((const float4*)in)[i];
        int c0 = (i << 2) & 63;
        ushort4 o;
        o.x = f2bf(fmaxf(sab[c0]     * v.x + sab[64 + c0],     0.f));
        o.y = f2bf(fmaxf(sab[c0 + 1] * v.y + sab[64 + c0 + 1], 0.f));
        o.z = f2bf(fmaxf(sab[c0 + 2] * v.z + sab[64 + c0 + 2], 0.f));
        o.w = f2bf(fmaxf(sab[c0 + 3] * v.w + sab[64 + c0 + 3], 0.f));
        ((ushort4*)out)[i] = o;
    }
}

#define MFMA(a, b, c) __builtin_amdgcn_mfma_f32_16x16x32_bf16(a, b, c, 0, 0, 0)
// lgkmcnt(0), vmcnt=no-wait(63), expcnt=no-wait(7)
#define WAIT_LGKM0() __builtin_amdgcn_s_waitcnt(0xC07F)

// --- conv1: LDS-shared-B gather->register MFMA sparse conv (R6 schedule) ----
// Block 256 thr (4 waves), 128 output rows; wave owns two 16-row m-tiles.
// Per k: block stages the 8KB B-set once (lane-contiguous uint4 ds_writes,
// conflict-free); A-frags gathered 2 iters ahead into a 3-deep reg buffer.
// Raw s_barrier + lgkmcnt(0) only -> A/B prefetches stay in flight.
// Epilogue transpose buffer ALIASES the B double-buffer (arena) -> ~18KB LDS.
__global__ __launch_bounds__(256, 4) void spconv(
        const unsigned short* __restrict__ h,     // [N,64] bf16 (post-BN1)
        const int* __restrict__ idx,              // [N,27]
        const unsigned short* __restrict__ Wf,    // packed frags [27][8][64][8]
        unsigned short* __restrict__ outb,        // conv1 out (bf16, raw)
        float* __restrict__ stats,                // conv1 fused stats
        int N) {
    __shared__ float4 arena[1088];                // 17408 B: sB[2][8KB] | sE 64x68 f32
    __shared__ float sred[128];
    unsigned short* sBb = (unsigned short*)arena; // sB[buf] = sBb + buf*4096
    float* sE = (float*)arena;

    int t = threadIdx.x, lane = t & 63, wid = t >> 6;
    int q = lane >> 4, l15 = lane & 15;
    int base = blockIdx.x * 128;
    if (t < 128) sred[t] = 0.f;

    int r0 = base + wid * 32 + l15;
    int r1 = r0 + 16;
    const int* ip0 = idx + (size_t)min(r0, N - 1) * KOFF;
    const int* ip1 = idx + (size_t)min(r1, N - 1) * KOFF;
    int qo = q * 8;

    floatx4 acc[2][4];
    #pragma unroll
    for (int a_ = 0; a_ < 2; ++a_)
        #pragma unroll
        for (int b_ = 0; b_ < 4; ++b_)
            acc[a_][b_] = floatx4{0.f, 0.f, 0.f, 0.f};

    // ---- prologue: A(0), A(1) gathers; B(0) staged+written; B(1) staged ----
    bf16x8 A0[4], A1[4], A2[4];
    {
        int g0 = ip0[0], g1 = ip1[0];
        const unsigned short* p0 = h + ((size_t)g0 << 6) + qo;
        const unsigned short* p1 = h + ((size_t)g1 << 6) + qo;
        A0[0] = *(const bf16x8*)p0; A0[1] = *(const bf16x8*)(p0 + 32);
        A0[2] = *(const bf16x8*)p1; A0[3] = *(const bf16x8*)(p1 + 32);
        g0 = ip0[1]; g1 = ip1[1];
        p0 = h + ((size_t)g0 << 6) + qo;
        p1 = h + ((size_t)g1 << 6) + qo;
        A1[0] = *(const bf16x8*)p0; A1[1] = *(const bf16x8*)(p0 + 32);
        A1[2] = *(const bf16x8*)p1; A1[3] = *(const bf16x8*)(p1 + 32);
    }
    int gc0 = ip0[2], gc1 = ip1[2];

    const uint4* Wf4 = (const uint4*)Wf;          // 8 shorts per uint4
    int so = wid * 64 + lane;                     // lane-contiguous slot
    uint4 bs0 = Wf4[so], bs1 = Wf4[256 + so];     // B(0)
    ((uint4*)sBb)[so] = bs0; ((uint4*)sBb)[256 + so] = bs1;
    bs0 = Wf4[512 + so]; bs1 = Wf4[512 + 256 + so];   // B(1) staged in regs

#define COMPUTE(ACUR, CB) {                                                    \
    const bf16x8* bp = (const bf16x8*)(sBb + (CB) * 4096);                     \
    bf16x8 f0 = bp[lane], f1 = bp[64 + lane], f2 = bp[128 + lane], f3 = bp[192 + lane]; \
    acc[0][0] = MFMA(ACUR[0], f0, acc[0][0]); acc[0][0] = MFMA(ACUR[1], f1, acc[0][0]); \
    acc[0][1] = MFMA(ACUR[0], f2, acc[0][1]); acc[0][1] = MFMA(ACUR[1], f3, acc[0][1]); \
    acc[1][0] = MFMA(ACUR[2], f0, acc[1][0]); acc[1][0] = MFMA(ACUR[3], f1, acc[1][0]); \
    acc[1][1] = MFMA(ACUR[2], f2, acc[1][1]); acc[1][1] = MFMA(ACUR[3], f3, acc[1][1]); \
    f0 = bp[256 + lane]; f1 = bp[320 + lane]; f2 = bp[384 + lane]; f3 = bp[448 + lane]; \
    acc[0][2] = MFMA(ACUR[0], f0, acc[0][2]); acc[0][2] = MFMA(ACUR[1], f1, acc[0][2]); \
    acc[0][3] = MFMA(ACUR[0], f2, acc[0][3]); acc[0][3] = MFMA(ACUR[1], f3, acc[0][3]); \
    acc[1][2] = MFMA(ACUR[2], f0, acc[1][2]); acc[1][2] = MFMA(ACUR[3], f1, acc[1][2]); \
    acc[1][3] = MFMA(ACUR[2], f2, acc[1][3]); acc[1][3] = MFMA(ACUR[3], f3, acc[1][3]); \
}

#define BODY_FULL(ACUR, ALD, KRT, CB, NB) {                                    \
    WAIT_LGKM0();                                                              \
    __builtin_amdgcn_s_barrier();                                              \
    ((uint4*)sBb)[(NB) * 512 + so] = bs0;                                      \
    ((uint4*)sBb)[(NB) * 512 + 256 + so] = bs1;                                \
    bs0 = Wf4[((KRT) + 2) * 512 + so]; bs1 = Wf4[((KRT) + 2) * 512 + 256 + so];\
    {                                                                          \
        const unsigned short* p0 = h + ((size_t)gc0 << 6) + qo;                \
        const unsigned short* p1 = h + ((size_t)gc1 << 6) + qo;                \
        ALD[0] = *(const bf16x8*)p0; ALD[1] = *(const bf16x8*)(p0 + 32);       \
        ALD[2] = *(const bf16x8*)p1; ALD[3] = *(const bf16x8*)(p1 + 32);       \
    }                                                                          \
    gc0 = ip0[(KRT) + 3]; gc1 = ip1[(KRT) + 3];                                \
    COMPUTE(ACUR, CB)                                                          \
}

    #pragma unroll 1
    for (int kk = 0; kk < 24; kk += 6) {
        BODY_FULL(A0, A2, kk + 0, 0, 1)
        BODY_FULL(A1, A0, kk + 1, 1, 0)
        BODY_FULL(A2, A1, kk + 2, 0, 1)
        BODY_FULL(A0, A2, kk + 3, 1, 0)
        BODY_FULL(A1, A0, kk + 4, 0, 1)
        BODY_FULL(A2, A1, kk + 5, 1, 0)
    }
    // k = 24: write B(25), stage B(26), gather A(26)
    {
        WAIT_LGKM0();
        __builtin_amdgcn_s_barrier();
        ((uint4*)sBb)[512 + so] = bs0; ((uint4*)sBb)[512 + 256 + so] = bs1;
        bs0 = Wf4[26 * 512 + so]; bs1 = Wf4[26 * 512 + 256 + so];
        {
            const unsigned short* p0 = h + ((size_t)gc0 << 6) + qo;
            const unsigned short* p1 = h + ((size_t)gc1 << 6) + qo;
            A2[0] = *(const bf16x8*)p0; A2[1] = *(const bf16x8*)(p0 + 32);
            A2[2] = *(const bf16x8*)p1; A2[3] = *(const bf16x8*)(p1 + 32);
        }
        COMPUTE(A0, 0)
    }
    // k = 25: write B(26)
    {
        WAIT_LGKM0();
        __builtin_amdgcn_s_barrier();
        ((uint4*)sBb)[so] = bs0; ((uint4*)sBb)[256 + so] = bs1;
        COMPUTE(A1, 1)
    }
    // k = 26
    {
        WAIT_LGKM0();
        __builtin_amdgcn_s_barrier();
        COMPUTE(A2, 0)
    }
#undef BODY_FULL

    // fused per-channel stats of conv1 output (tail rows masked)
    #pragma unroll
    for (int ct = 0; ct < 4; ++ct) {
        float s1 = 0.f, s2 = 0.f;
        #pragma unroll
        for (int rt = 0; rt < 2; ++rt)
            #pragma unroll
            for (int r = 0; r < 4; ++r) {
                int rowc = base + wid * 32 + rt * 16 + q * 4 + r;
                float vv = (rowc < N) ? acc[rt][ct][r] : 0.f;
                s1 += vv; s2 += vv * vv;
            }
        s1 += __shfl_xor(s1, 16); s2 += __shfl_xor(s2, 16);
        s1 += __shfl_xor(s1, 32); s2 += __shfl_xor(s2, 32);
        if (q == 0) {
            atomicAdd(&sred[ct * 16 + l15], s1);
            atomicAdd(&sred[64 + ct * 16 + l15], s2);
        }
    }

    __syncthreads();   // all sB reads done before sE (alias) is written

    // epilogue: two 64-row halves through the arena (aliases sB)
    #pragma unroll
    for (int hf = 0; hf < 2; ++hf) {
        if ((wid >> 1) == hf) {
            int lrow0 = (wid & 1) * 32;
            #pragma unroll
            for (int rt = 0; rt < 2; ++rt)
                #pragma unroll
                for (int ct = 0; ct < 4; ++ct)
                    #pragma unroll
                    for (int r = 0; r < 4; ++r)
                        sE[(lrow0 + rt * 16 + q * 4 + r) * 68 + ct * 16 + l15] = acc[rt][ct][r];
        }
        __syncthreads();
        if (hf == 0 && t < 64) {
            atomicAdd(&stats[t], sred[t]);
            atomicAdd(&stats[64 + t], sred[64 + t]);
        }
        int rr = t >> 2, cc = t & 3;
        int grow = base + hf * 64 + rr;
        if (grow < N) {
            const float* sp = sE + rr * 68 + cc * 16;
            unsigned short o[16];
            #pragma unroll
            for (int j = 0; j < 16; ++j) o[j] = f2bf(sp[j]);
            unsigned short* op = outb + ((size_t)grow << 6) + cc * 16;
            ((uint4*)op)[0] = *(const uint4*)(o);
            ((uint4*)op)[1] = *(const uint4*)(o + 8);
        }
        if (hf == 0) __syncthreads();
    }
}

// --- conv2: same schedule + fused input BN2+ReLU at A-consume time ----------
// Identical math to the deleted bn_relu_b16 pass (bf16 in -> f32 a*v+b ->
// relu -> RNE bf16), applied to each gathered fragment before MFMA.
// launch_bounds(256,3): 170-reg cap (vs 128 at min-waves=4) -> no spill;
// achieved occupancy (~10.4 waves/CU) is below the 12-wave cap, so free.
__global__ __launch_bounds__(256, 3) void spconv2bn(
        const unsigned short* __restrict__ h,     // [N,64] bf16 conv1 raw out
        const int* __restrict__ idx,              // [N,27]
        const unsigned short* __restrict__ Wf,    // packed frags [27][8][64][8]
        float* __restrict__ outf,                 // conv2 out (fp32)
        const float* __restrict__ resid,          // residual (x)
        const float* __restrict__ bnsums,         // conv1-output raw sums
        const float* __restrict__ gamma, const float* __restrict__ beta,
        float invN, int N) {
    __shared__ float4 arena[1088];                // 17408 B: sB[2][8KB] | sE 64x68 f32
    __shared__ float sab[128];
    unsigned short* sBb = (unsigned short*)arena;
    float* sE = (float*)arena;

    int t = threadIdx.x, lane = t & 63, wid = t >> 6;
    int q = lane >> 4, l15 = lane & 15;
    int base = blockIdx.x * 128;

    int r0 = base + wid * 32 + l15;
    int r1 = r0 + 16;
    const int* ip0 = idx + (size_t)min(r0, N - 1) * KOFF;
    const int* ip1 = idx + (size_t)min(r1, N - 1) * KOFF;
    int qo = q * 8;

    // BN coefficients -> LDS -> per-lane registers (16 channels per lane)
    if (t < 64) {
        float mu  = bnsums[t] * invN;
        float var = fmaxf(bnsums[64 + t] * invN - mu * mu, 0.f);
        float a   = gamma[t] * rsqrtf(var + 1e-5f);
        sab[t] = a; sab[64 + t] = beta[t] - mu * a;
    }
    __syncthreads();
    float fa0[8], fb0[8], fa1[8], fb1[8];
    #pragma unroll
    for (int j = 0; j < 8; ++j) {
        fa0[j] = sab[qo + j];      fb0[j] = sab[64 + qo + j];
        fa1[j] = sab[32 + qo + j]; fb1[j] = sab[64 + 32 + qo + j];
    }

    floatx4 acc[2][4];
    #pragma unroll
    for (int a_ = 0; a_ < 2; ++a_)
        #pragma unroll
        for (int b_ = 0; b_ < 4; ++b_)
            acc[a_][b_] = floatx4{0.f, 0.f, 0.f, 0.f};

    // ---- prologue ----
    bf16x8 A0[4], A1[4], A2[4];
    {
        int g0 = ip0[0], g1 = ip1[0];
        const unsigned short* p0 = h + ((size_t)g0 << 6) + qo;
        const unsigned short* p1 = h + ((size_t)g1 << 6) + qo;
        A0[0] = *(const bf16x8*)p0; A0[1] = *(const bf16x8*)(p0 + 32);
        A0[2] = *(const bf16x8*)p1; A0[3] = *(const bf16x8*)(p1 + 32);
        g0 = ip0[1]; g1 = ip1[1];
        p0 = h + ((size_t)g0 << 6) + qo;
        p1 = h + ((size_t)g1 << 6) + qo;
        A1[0] = *(const bf16x8*)p0; A1[1] = *(const bf16x8*)(p0 + 32);
        A1[2] = *(const bf16x8*)p1; A1[3] = *(const bf16x8*)(p1 + 32);
    }
    int gc0 = ip0[2], gc1 = ip1[2];

    const uint4* Wf4 = (const uint4*)Wf;
    int so = wid * 64 + lane;
    uint4 bs0 = Wf4[so], bs1 = Wf4[256 + so];
    ((uint4*)sBb)[so] = bs0; ((uint4*)sBb)[256 + so] = bs1;
    bs0 = Wf4[512 + so]; bs1 = Wf4[512 + 256 + so];

// BN+ReLU applied to the 4 gathered fragments, then same MFMA block.
#define COMPUTE2(ACUR, CB) {                                                   \
    bf16x8 t0_, t1_, t2_, t3_;                                                 \
    _Pragma("unroll")                                                          \
    for (int j_ = 0; j_ < 8; ++j_) {                                           \
        t0_[j_] = (__bf16)fmaxf(fa0[j_] * (float)ACUR[0][j_] + fb0[j_], 0.f);  \
        t1_[j_] = (__bf16)fmaxf(fa1[j_] * (float)ACUR[1][j_] + fb1[j_], 0.f);  \
        t2_[j_] = (__bf16)fmaxf(fa0[j_] * (float)ACUR[2][j_] + fb0[j_], 0.f);  \
        t3_[j_] = (__bf16)fmaxf(fa1[j_] * (float)ACUR[3][j_] + fb1[j_], 0.f);  \
    }                                                                          \
    const bf16x8* bp = (const bf16x8*)(sBb + (CB) * 4096);                     \
    bf16x8 f0 = bp[lane], f1 = bp[64 + lane], f2 = bp[128 + lane], f3 = bp[192 + lane]; \
    acc[0][0] = MFMA(t0_, f0, acc[0][0]); acc[0][0] = MFMA(t1_, f1, acc[0][0]); \
    acc[0][1] = MFMA(t0_, f2, acc[0][1]); acc[0][1] = MFMA(t1_, f3, acc[0][1]); \
    acc[1][0] = MFMA(t2_, f0, acc[1][0]); acc[1][0] = MFMA(t3_, f1, acc[1][0]); \
    acc[1][1] = MFMA(t2_, f2, acc[1][1]); acc[1][1] = MFMA(t3_, f3, acc[1][1]); \
    f0 = bp[256 + lane]; f1 = bp[320 + lane]; f2 = bp[384 + lane]; f3 = bp[448 + lane]; \
    acc[0][2] = MFMA(t0_, f0, acc[0][2]); acc[0][2] = MFMA(t1_, f1, acc[0][2]); \
    acc[0][3] = MFMA(t0_, f2, acc[0][3]); acc[0][3] = MFMA(t1_, f3, acc[0][3]); \
    acc[1][2] = MFMA(t2_, f0, acc[1][2]); acc[1][2] = MFMA(t3_, f1, acc[1][2]); \
    acc[1][3] = MFMA(t2_, f2, acc[1][3]); acc[1][3] = MFMA(t3_, f3, acc[1][3]); \
}

#define BODY2(ACUR, ALD, KRT, CB, NB) {                                        \
    WAIT_LGKM0();                                                              \
    __builtin_amdgcn_s_barrier();                                              \
    ((uint4*)sBb)[(NB) * 512 + so] = bs0;                                      \
    ((uint4*)sBb)[(NB) * 512 + 256 + so] = bs1;                                \
    bs0 = Wf4[((KRT) + 2) * 512 + so]; bs1 = Wf4[((KRT) + 2) * 512 + 256 + so];\
    {                                                                          \
        const unsigned short* p0 = h + ((size_t)gc0 << 6) + qo;                \
        const unsigned short* p1 = h + ((size_t)gc1 << 6) + qo;                \
        ALD[0] = *(const bf16x8*)p0; ALD[1] = *(const bf16x8*)(p0 + 32);       \
        ALD[2] = *(const bf16x8*)p1; ALD[3] = *(const bf16x8*)(p1 + 32);       \
    }                                                                          \
    gc0 = ip0[(KRT) + 3]; gc1 = ip1[(KRT) + 3];                                \
    COMPUTE2(ACUR, CB)                                                         \
}

    #pragma unroll 1
    for (int kk = 0; kk < 24; kk += 6) {
        BODY2(A0, A2, kk + 0, 0, 1)
        BODY2(A1, A0, kk + 1, 1, 0)
        BODY2(A2, A1, kk + 2, 0, 1)
        BODY2(A0, A2, kk + 3, 1, 0)
        BODY2(A1, A0, kk + 4, 0, 1)
        BODY2(A2, A1, kk + 5, 1, 0)
    }
    // k = 24
    {
        WAIT_LGKM0();
        __builtin_amdgcn_s_barrier();
        ((uint4*)sBb)[512 + so] = bs0; ((uint4*)sBb)[512 + 256 + so] = bs1;
        bs0 = Wf4[26 * 512 + so]; bs1 = Wf4[26 * 512 + 256 + so];
        {
            const unsigned short* p0 = h + ((size_t)gc0 << 6) + qo;
            const unsigned short* p1 = h + ((size_t)gc1 << 6) + qo;
            A2[0] = *(const bf16x8*)p0; A2[1] = *(const bf16x8*)(p0 + 32);
            A2[2] = *(const bf16x8*)p1; A2[3] = *(const bf16x8*)(p1 + 32);
        }
        COMPUTE2(A0, 0)
    }
    // k = 25
    {
        WAIT_LGKM0();
        __builtin_amdgcn_s_barrier();
        ((uint4*)sBb)[so] = bs0; ((uint4*)sBb)[256 + so] = bs1;
        COMPUTE2(A1, 1)
    }
    // k = 26
    {
        WAIT_LGKM0();
        __builtin_amdgcn_s_barrier();
        COMPUTE2(A2, 0)
    }
#undef BODY2
#undef COMPUTE2

    __syncthreads();   // all sB reads done before sE (alias) is written

    // epilogue: two 64-row halves through the arena; add residual, fp32 out
    #pragma unroll
    for (int hf = 0; hf < 2; ++hf) {
        if ((wid >> 1) == hf) {
            int lrow0 = (wid & 1) * 32;
            #pragma unroll
            for (int rt = 0; rt < 2; ++rt)
                #pragma unroll
                for (int ct = 0; ct < 4; ++ct)
                    #pragma unroll
                    for (int r = 0; r < 4; ++r)
                        sE[(lrow0 + rt * 16 + q * 4 + r) * 68 + ct * 16 + l15] = acc[rt][ct][r];
        }
        __syncthreads();
        int rr = t >> 2, cc = t & 3;
        int grow = base + hf * 64 + rr;
        if (grow < N) {
            const float* sp = sE + rr * 68 + cc * 16;
            const float* rp = resid + ((size_t)grow << 6) + cc * 16;
            float* op = outf + ((size_t)grow << 6) + cc * 16;
            #pragma unroll
            for (int j = 0; j < 4; ++j) {
                float4 v = *(const float4*)(sp + j * 4);
                float4 rv = *(const float4*)(rp + j * 4);
                v.x += rv.x; v.y += rv.y; v.z += rv.z; v.w += rv.w;
                *(float4*)(op + j * 4) = v;
            }
        }
        if (hf == 0) __syncthreads();
    }
}
#undef COMPUTE

// ---------------------------------------------------------------------------
extern "C" void kernel_launch(void* const* d_in, const int* in_sizes, int n_in,
                              void* d_out, int out_size, void* d_ws, size_t ws_size,
                              hipStream_t stream) {
    const float* x      = (const float*)d_in[0];
    const int*   nbr    = (const int*)  d_in[1];
    const float* W1     = (const float*)d_in[2];
    const float* gamma1 = (const float*)d_in[3];
    const float* beta1  = (const float*)d_in[4];
    const float* W2     = (const float*)d_in[5];
    const float* gamma2 = (const float*)d_in[6];
    const float* beta2  = (const float*)d_in[7];
    float* out = (float*)d_out;

    int N = in_sizes[0] / 64;
    float invN = 1.0f / (float)N;

    char* ws = (char*)d_ws;
    float*          stats = (float*)ws;                           // 512 floats
    unsigned short* W1f   = (unsigned short*)(ws + 4096);         // 110592 bf16
    unsigned short* W2f   = W1f + 110592;
    unsigned short* hbuf  = W2f + 110592;                         // [N,64] bf16
    unsigned short* out1b = hbuf + (size_t)N * 64;                // [N,64] bf16

    int nb = (N + 127) / 128;

    hipMemsetAsync(stats, 0, 2048, stream);
    prep2<<<54 + 512, 256, 0, stream>>>(W1, W2, W1f, W2f, x, stats, N * 16);
    bn_relu_f32<<<768, 256, 0, stream>>>(x, stats, gamma1, beta1, hbuf, N * 16, invN);
    // conv1: input already BN'd (hbuf); writes raw bf16 conv out + fused stats
    spconv<<<nb, 256, 0, stream>>>(hbuf, nbr, W1f, out1b, stats + 256, N);
    // conv2: BN2+ReLU fused at gather-consume; adds residual; fp32 out
    spconv2bn<<<nb, 256, 0, stream>>>(out1b, nbr, W2f, out, x,
                                      stats + 256, gamma2, beta2, invN, N);
}

// Round 9
// 405.474 us; speedup vs baseline: 1.2793x; 1.2793x over previous
//
#include <hip/hip_runtime.h>

// ---------------------------------------------------------------------------
// ResNet sparse-conv block, round 12: best-known configuration. Exact R6
// spconv schedule (3-deep A ring, ds_write B staging, lgkm-only waits) run
// for both convs; float4 prep2 stats (twice-confirmed -20us); separate
// bn_relu_f32 / bn_relu_b16 passes. BN-fusion abandoned per pre-registered
// rule (two scratch-spill signatures: R8 +101MB, R11b +237MB symmetric).
// ---------------------------------------------------------------------------

#define KOFF 27

typedef __bf16 bf16x8 __attribute__((ext_vector_type(8)));
typedef float floatx4 __attribute__((ext_vector_type(4)));

__device__ __forceinline__ unsigned short f2bf(float x) {
    union { float f; unsigned int u; } v; v.f = x;
    unsigned int u = v.u;
    unsigned int r = u + 0x7FFFu + ((u >> 16) & 1u);
    return (unsigned short)(r >> 16);
}
__device__ __forceinline__ float bf2f(unsigned short s) {
    union { float f; unsigned int u; } v; v.u = ((unsigned int)s) << 16; return v.f;
}

// --- prep: blocks 0..53 pack W (coalesced, LDS transpose); rest: x stats ----
// frag element j of (ct,ks) for lane (q,l15) = W[k][cin=ks*32+q*8+j][cout=ct*16+l15]
__global__ void prep2(const float* __restrict__ W1, const float* __restrict__ W2,
                      unsigned short* __restrict__ W1f, unsigned short* __restrict__ W2f,
                      const float* __restrict__ x, float* __restrict__ stats,
                      int total4) {
    int b = blockIdx.x, t = threadIdx.x;
    if (b < 54) {
        __shared__ float sW[64 * 68];
        int k = b % 27;
        const float* src = (b < 27 ? W1 : W2) + k * 4096;
        unsigned short* dst = (b < 27 ? W1f : W2f) + (size_t)k * 4096;
        #pragma unroll
        for (int i = 0; i < 4; ++i) {
            int i4 = t + i * 256;
            float4 v = ((const float4*)src)[i4];
            int f = i4 * 4, r = f >> 6, c = f & 63;
            sW[r * 68 + c]     = v.x;
            sW[r * 68 + c + 1] = v.y;
            sW[r * 68 + c + 2] = v.z;
            sW[r * 68 + c + 3] = v.w;
        }
        __syncthreads();
        int fi = (t >> 5) & 7, ct = fi >> 1, ks = fi & 1;
        unsigned short o[16];
        #pragma unroll
        for (int d = 0; d < 2; ++d) {
            int lane2 = (t * 2 + d) & 63, q = lane2 >> 4, l15 = lane2 & 15;
            #pragma unroll
            for (int j = 0; j < 8; ++j) {
                int cin = ks * 32 + q * 8 + j, cout = ct * 16 + l15;
                o[d * 8 + j] = f2bf(sW[cin * 68 + cout]);
            }
        }
        ((uint4*)(dst + t * 16))[0] = *(const uint4*)(o);
        ((uint4*)(dst + t * 16))[1] = *(const uint4*)(o + 8);
        return;
    }
    __shared__ float s[128];
    if (t < 128) s[t] = 0.f;
    __syncthreads();
    int i = (b - 54) * 256 + t;
    int stride = (gridDim.x - 54) * 256;
    // float4 loads; channel of component 0 is (4t)&63 (block/grid strides are
    // multiples of 64 channels).
    float a0 = 0.f, a1 = 0.f, a2 = 0.f, a3 = 0.f;
    float b0 = 0.f, b1 = 0.f, b2 = 0.f, b3 = 0.f;
    for (; i < total4; i += stride) {
        float4 v = ((const float4*)x)[i];
        a0 += v.x; b0 += v.x * v.x;
        a1 += v.y; b1 += v.y * v.y;
        a2 += v.z; b2 += v.z * v.z;
        a3 += v.w; b3 += v.w * v.w;
    }
    int c0 = (t << 2) & 63;
    atomicAdd(&s[c0],     a0); atomicAdd(&s[c0 + 1],     a1);
    atomicAdd(&s[c0 + 2], a2); atomicAdd(&s[c0 + 3],     a3);
    atomicAdd(&s[64 + c0],     b0); atomicAdd(&s[64 + c0 + 1], b1);
    atomicAdd(&s[64 + c0 + 2], b2); atomicAdd(&s[64 + c0 + 3], b3);
    __syncthreads();
    if (t < 64) { atomicAdd(&stats[t], s[t]); atomicAdd(&stats[64 + t], s[64 + t]); }
}

// --- BN + ReLU + bf16 cast, fp32 input --------------------------------------
__global__ void bn_relu_f32(const float* __restrict__ in, const float* __restrict__ sums,
                            const float* __restrict__ gamma, const float* __restrict__ beta,
                            unsigned short* __restrict__ out, int total4, float invN) {
    __shared__ float sab[128];
    int t = threadIdx.x;
    if (t < 64) {
        float mu  = sums[t] * invN;
        float var = fmaxf(sums[64 + t] * invN - mu * mu, 0.f);
        float a   = gamma[t] * rsqrtf(var + 1e-5f);
        sab[t] = a; sab[64 + t] = beta[t] - mu * a;
    }
    __syncthreads();
    int i = blockIdx.x * blockDim.x + t;
    int stride = gridDim.x * blockDim.x;
    for (; i < total4; i += stride) {
        float4 v = ((const float4*)in)[i];
        int c0 = (i << 2) & 63;
        ushort4 o;
        o.x = f2bf(fmaxf(sab[c0]     * v.x + sab[64 + c0],     0.f));
        o.y = f2bf(fmaxf(sab[c0 + 1] * v.y + sab[64 + c0 + 1], 0.f));
        o.z = f2bf(fmaxf(sab[c0 + 2] * v.z + sab[64 + c0 + 2], 0.f));
        o.w = f2bf(fmaxf(sab[c0 + 3] * v.w + sab[64 + c0 + 3], 0.f));
        ((ushort4*)out)[i] = o;
    }
}

// --- BN + ReLU + bf16 cast, bf16 input --------------------------------------
__global__ void bn_relu_b16(const unsigned short* __restrict__ in, const float* __restrict__ sums,
                            const float* __restrict__ gamma, const float* __restrict__ beta,
                            unsigned short* __restrict__ out, int total8, float invN) {
    __shared__ float sab[128];
    int t = threadIdx.x;
    if (t < 64) {
        float mu  = sums[t] * invN;
        float var = fmaxf(sums[64 + t] * invN - mu * mu, 0.f);
        float a   = gamma[t] * rsqrtf(var + 1e-5f);
        sab[t] = a; sab[64 + t] = beta[t] - mu * a;
    }
    __syncthreads();
    int i = blockIdx.x * blockDim.x + t;
    int stride = gridDim.x * blockDim.x;
    for (; i < total8; i += stride) {
        uint4 v = ((const uint4*)in)[i];
        int c0 = (i << 3) & 63;
        unsigned int w[4] = {v.x, v.y, v.z, v.w};
        unsigned int o[4];
        #pragma unroll
        for (int p = 0; p < 4; ++p) {
            float f0 = bf2f((unsigned short)(w[p] & 0xffff));
            float f1 = bf2f((unsigned short)(w[p] >> 16));
            int c = c0 + p * 2;
            unsigned short r0 = f2bf(fmaxf(sab[c]     * f0 + sab[64 + c],     0.f));
            unsigned short r1 = f2bf(fmaxf(sab[c + 1] * f1 + sab[64 + c + 1], 0.f));
            o[p] = (unsigned int)r0 | ((unsigned int)r1 << 16);
        }
        ((uint4*)out)[i] = make_uint4(o[0], o[1], o[2], o[3]);
    }
}

#define MFMA(a, b, c) __builtin_amdgcn_mfma_f32_16x16x32_bf16(a, b, c, 0, 0, 0)
// lgkmcnt(0), vmcnt=no-wait(63), expcnt=no-wait(7)
#define WAIT_LGKM0() __builtin_amdgcn_s_waitcnt(0xC07F)

// --- LDS-shared-B gather->register MFMA sparse conv (R6 schedule) -----------
// Block 256 thr (4 waves), 128 output rows; wave owns two 16-row m-tiles.
// Per k: block stages the 8KB B-set once (lane-contiguous uint4 ds_writes,
// conflict-free); A-frags gathered 2 iters ahead into a 3-deep reg buffer.
// Raw s_barrier + lgkmcnt(0) only -> A/B prefetches stay in flight.
// Epilogue transpose buffer ALIASES the B double-buffer (arena) -> ~18KB LDS.
__global__ __launch_bounds__(256, 4) void spconv(
        const unsigned short* __restrict__ h,     // [N,64] bf16
        const int* __restrict__ idx,              // [N,27]
        const unsigned short* __restrict__ Wf,    // packed frags [27][8][64][8]
        unsigned short* __restrict__ outb,        // conv1 out (bf16) or null
        float* __restrict__ outf,                 // conv2 out (fp32) or null
        const float* __restrict__ resid,          // conv2 residual or null
        float* __restrict__ stats,                // conv1 fused stats or null
        int N) {
    __shared__ float4 arena[1088];                // 17408 B: sB[2][8KB] | sE 64x68 f32
    __shared__ float sred[128];
    unsigned short* sBb = (unsigned short*)arena; // sB[buf] = sBb + buf*4096
    float* sE = (float*)arena;

    int t = threadIdx.x, lane = t & 63, wid = t >> 6;
    int q = lane >> 4, l15 = lane & 15;
    int base = blockIdx.x * 128;
    if (t < 128) sred[t] = 0.f;

    int r0 = base + wid * 32 + l15;
    int r1 = r0 + 16;
    const int* ip0 = idx + (size_t)min(r0, N - 1) * KOFF;
    const int* ip1 = idx + (size_t)min(r1, N - 1) * KOFF;
    int qo = q * 8;

    floatx4 acc[2][4];
    #pragma unroll
    for (int a_ = 0; a_ < 2; ++a_)
        #pragma unroll
        for (int b_ = 0; b_ < 4; ++b_)
            acc[a_][b_] = floatx4{0.f, 0.f, 0.f, 0.f};

    // ---- prologue: A(0), A(1) gathers; B(0) staged+written; B(1) staged ----
    bf16x8 A0[4], A1[4], A2[4];
    {
        int g0 = ip0[0], g1 = ip1[0];
        const unsigned short* p0 = h + ((size_t)g0 << 6) + qo;
        const unsigned short* p1 = h + ((size_t)g1 << 6) + qo;
        A0[0] = *(const bf16x8*)p0; A0[1] = *(const bf16x8*)(p0 + 32);
        A0[2] = *(const bf16x8*)p1; A0[3] = *(const bf16x8*)(p1 + 32);
        g0 = ip0[1]; g1 = ip1[1];
        p0 = h + ((size_t)g0 << 6) + qo;
        p1 = h + ((size_t)g1 << 6) + qo;
        A1[0] = *(const bf16x8*)p0; A1[1] = *(const bf16x8*)(p0 + 32);
        A1[2] = *(const bf16x8*)p1; A1[3] = *(const bf16x8*)(p1 + 32);
    }
    int gc0 = ip0[2], gc1 = ip1[2];

    const uint4* Wf4 = (const uint4*)Wf;          // 8 shorts per uint4
    int so = wid * 64 + lane;                     // lane-contiguous slot
    uint4 bs0 = Wf4[so], bs1 = Wf4[256 + so];     // B(0)
    ((uint4*)sBb)[so] = bs0; ((uint4*)sBb)[256 + so] = bs1;
    bs0 = Wf4[512 + so]; bs1 = Wf4[512 + 256 + so];   // B(1) staged in regs

#define COMPUTE(ACUR, CB) {                                                    \
    const bf16x8* bp = (const bf16x8*)(sBb + (CB) * 4096);                     \
    bf16x8 f0 = bp[lane], f1 = bp[64 + lane], f2 = bp[128 + lane], f3 = bp[192 + lane]; \
    acc[0][0] = MFMA(ACUR[0], f0, acc[0][0]); acc[0][0] = MFMA(ACUR[1], f1, acc[0][0]); \
    acc[0][1] = MFMA(ACUR[0], f2, acc[0][1]); acc[0][1] = MFMA(ACUR[1], f3, acc[0][1]); \
    acc[1][0] = MFMA(ACUR[2], f0, acc[1][0]); acc[1][0] = MFMA(ACUR[3], f1, acc[1][0]); \
    acc[1][1] = MFMA(ACUR[2], f2, acc[1][1]); acc[1][1] = MFMA(ACUR[3], f3, acc[1][1]); \
    f0 = bp[256 + lane]; f1 = bp[320 + lane]; f2 = bp[384 + lane]; f3 = bp[448 + lane]; \
    acc[0][2] = MFMA(ACUR[0], f0, acc[0][2]); acc[0][2] = MFMA(ACUR[1], f1, acc[0][2]); \
    acc[0][3] = MFMA(ACUR[0], f2, acc[0][3]); acc[0][3] = MFMA(ACUR[1], f3, acc[0][3]); \
    acc[1][2] = MFMA(ACUR[2], f0, acc[1][2]); acc[1][2] = MFMA(ACUR[3], f1, acc[1][2]); \
    acc[1][3] = MFMA(ACUR[2], f2, acc[1][3]); acc[1][3] = MFMA(ACUR[3], f3, acc[1][3]); \
}

#define BODY_FULL(ACUR, ALD, KRT, CB, NB) {                                    \
    WAIT_LGKM0();                                                              \
    __builtin_amdgcn_s_barrier();                                              \
    ((uint4*)sBb)[(NB) * 512 + so] = bs0;                                      \
    ((uint4*)sBb)[(NB) * 512 + 256 + so] = bs1;                                \
    bs0 = Wf4[((KRT) + 2) * 512 + so]; bs1 = Wf4[((KRT) + 2) * 512 + 256 + so];\
    {                                                                          \
        const unsigned short* p0 = h + ((size_t)gc0 << 6) + qo;                \
        const unsigned short* p1 = h + ((size_t)gc1 << 6) + qo;                \
        ALD[0] = *(const bf16x8*)p0; ALD[1] = *(const bf16x8*)(p0 + 32);       \
        ALD[2] = *(const bf16x8*)p1; ALD[3] = *(const bf16x8*)(p1 + 32);       \
    }                                                                          \
    gc0 = ip0[(KRT) + 3]; gc1 = ip1[(KRT) + 3];                                \
    COMPUTE(ACUR, CB)                                                          \
}

    #pragma unroll 1
    for (int kk = 0; kk < 24; kk += 6) {
        BODY_FULL(A0, A2, kk + 0, 0, 1)
        BODY_FULL(A1, A0, kk + 1, 1, 0)
        BODY_FULL(A2, A1, kk + 2, 0, 1)
        BODY_FULL(A0, A2, kk + 3, 1, 0)
        BODY_FULL(A1, A0, kk + 4, 0, 1)
        BODY_FULL(A2, A1, kk + 5, 1, 0)
    }
    // k = 24: write B(25), stage B(26), gather A(26)
    {
        WAIT_LGKM0();
        __builtin_amdgcn_s_barrier();
        ((uint4*)sBb)[512 + so] = bs0; ((uint4*)sBb)[512 + 256 + so] = bs1;
        bs0 = Wf4[26 * 512 + so]; bs1 = Wf4[26 * 512 + 256 + so];
        {
            const unsigned short* p0 = h + ((size_t)gc0 << 6) + qo;
            const unsigned short* p1 = h + ((size_t)gc1 << 6) + qo;
            A2[0] = *(const bf16x8*)p0; A2[1] = *(const bf16x8*)(p0 + 32);
            A2[2] = *(const bf16x8*)p1; A2[3] = *(const bf16x8*)(p1 + 32);
        }
        COMPUTE(A0, 0)
    }
    // k = 25: write B(26)
    {
        WAIT_LGKM0();
        __builtin_amdgcn_s_barrier();
        ((uint4*)sBb)[so] = bs0; ((uint4*)sBb)[256 + so] = bs1;
        COMPUTE(A1, 1)
    }
    // k = 26
    {
        WAIT_LGKM0();
        __builtin_amdgcn_s_barrier();
        COMPUTE(A2, 0)
    }
#undef BODY_FULL
#undef COMPUTE

    // fused per-channel stats of conv1 output (tail rows masked)
    if (stats) {
        #pragma unroll
        for (int ct = 0; ct < 4; ++ct) {
            float s1 = 0.f, s2 = 0.f;
            #pragma unroll
            for (int rt = 0; rt < 2; ++rt)
                #pragma unroll
                for (int r = 0; r < 4; ++r) {
                    int rowc = base + wid * 32 + rt * 16 + q * 4 + r;
                    float vv = (rowc < N) ? acc[rt][ct][r] : 0.f;
                    s1 += vv; s2 += vv * vv;
                }
            s1 += __shfl_xor(s1, 16); s2 += __shfl_xor(s2, 16);
            s1 += __shfl_xor(s1, 32); s2 += __shfl_xor(s2, 32);
            if (q == 0) {
                atomicAdd(&sred[ct * 16 + l15], s1);
                atomicAdd(&sred[64 + ct * 16 + l15], s2);
            }
        }
    }

    __syncthreads();   // all sB reads done before sE (alias) is written

    // epilogue: two 64-row halves through the arena (aliases sB)
    #pragma unroll
    for (int hf = 0; hf < 2; ++hf) {
        if ((wid >> 1) == hf) {
            int lrow0 = (wid & 1) * 32;
            #pragma unroll
            for (int rt = 0; rt < 2; ++rt)
                #pragma unroll
                for (int ct = 0; ct < 4; ++ct)
                    #pragma unroll
                    for (int r = 0; r < 4; ++r)
                        sE[(lrow0 + rt * 16 + q * 4 + r) * 68 + ct * 16 + l15] = acc[rt][ct][r];
        }
        __syncthreads();
        if (hf == 0 && stats && t < 64) {
            atomicAdd(&stats[t], sred[t]);
            atomicAdd(&stats[64 + t], sred[64 + t]);
        }
        int rr = t >> 2, cc = t & 3;
        int grow = base + hf * 64 + rr;
        if (grow < N) {
            const float* sp = sE + rr * 68 + cc * 16;
            if (outb) {
                unsigned short o[16];
                #pragma unroll
                for (int j = 0; j < 16; ++j) o[j] = f2bf(sp[j]);
                unsigned short* op = outb + ((size_t)grow << 6) + cc * 16;
                ((uint4*)op)[0] = *(const uint4*)(o);
                ((uint4*)op)[1] = *(const uint4*)(o + 8);
            } else {
                const float* rp = resid + ((size_t)grow << 6) + cc * 16;
                float* op = outf + ((size_t)grow << 6) + cc * 16;
                #pragma unroll
                for (int j = 0; j < 4; ++j) {
                    float4 v = *(const float4*)(sp + j * 4);
                    float4 rv = *(const float4*)(rp + j * 4);
                    v.x += rv.x; v.y += rv.y; v.z += rv.z; v.w += rv.w;
                    *(float4*)(op + j * 4) = v;
                }
            }
        }
        if (hf == 0) __syncthreads();
    }
}

// ---------------------------------------------------------------------------
extern "C" void kernel_launch(void* const* d_in, const int* in_sizes, int n_in,
                              void* d_out, int out_size, void* d_ws, size_t ws_size,
                              hipStream_t stream) {
    const float* x      = (const float*)d_in[0];
    const int*   nbr    = (const int*)  d_in[1];
    const float* W1     = (const float*)d_in[2];
    const float* gamma1 = (const float*)d_in[3];
    const float* beta1  = (const float*)d_in[4];
    const float* W2     = (const float*)d_in[5];
    const float* gamma2 = (const float*)d_in[6];
    const float* beta2  = (const float*)d_in[7];
    float* out = (float*)d_out;

    int N = in_sizes[0] / 64;
    float invN = 1.0f / (float)N;

    char* ws = (char*)d_ws;
    float*          stats = (float*)ws;                           // 512 floats
    unsigned short* W1f   = (unsigned short*)(ws + 4096);         // 110592 bf16
    unsigned short* W2f   = W1f + 110592;
    unsigned short* hbuf  = W2f + 110592;                         // [N,64] bf16
    unsigned short* out1b = hbuf + (size_t)N * 64;                // [N,64] bf16

    int nb = (N + 127) / 128;

    hipMemsetAsync(stats, 0, 2048, stream);
    prep2<<<54 + 512, 256, 0, stream>>>(W1, W2, W1f, W2f, x, stats, N * 16);
    bn_relu_f32<<<768, 256, 0, stream>>>(x, stats, gamma1, beta1, hbuf, N * 16, invN);
    spconv<<<nb, 256, 0, stream>>>(hbuf, nbr, W1f, out1b, nullptr, nullptr, stats + 256, N);
    bn_relu_b16<<<768, 256, 0, stream>>>(out1b, stats + 256, gamma2, beta2, hbuf, N * 8, invN);
    spconv<<<nb, 256, 0, stream>>>(hbuf, nbr, W2f, nullptr, out, x, nullptr, N);
}